// Round 8
// baseline (102.882 us; speedup 1.0000x reference)
//
#include <hip/hip_runtime.h>
#include <math.h>

// Problem constants (RelTransformerActor)
namespace {
constexpr int B_  = 128;
constexpr int T_  = 128;
constexpr int K_  = 8;
constexpr int H_  = 3;
constexpr int HK_ = 24;
constexpr int HID_ = 256;
constexpr int OUT_ = 2;
constexpr int PBS_ = 136;  // Pb row stride (bf16): 272B, 16B-aligned, lq-groups 16 banks apart
}

typedef __attribute__((ext_vector_type(8))) short bf16x8;
typedef __attribute__((ext_vector_type(4))) float f32x4;

__device__ inline unsigned short f2bf(float x) {           // RNE fp32->bf16
    unsigned int u = __float_as_uint(x);
    u += 0x7FFFu + ((u >> 16) & 1u);
    return (unsigned short)(u >> 16);
}
__device__ inline float bf2f(unsigned short v) { return __uint_as_float((unsigned)v << 16); }

// Cross-lane add via DPP (VALU pipe, not DS).
template <int CTRL>
__device__ inline float dpp_add(float v) {
    int t = __builtin_amdgcn_update_dpp(0, __float_as_int(v), CTRL, 0xF, 0xF, true);
    return v + __int_as_float(t);
}
__device__ inline float red16(float v) {   // sum over 16-lane groups
    v = dpp_add<0xB1>(v);     // quad_perm lane^1
    v = dpp_add<0x4E>(v);     // quad_perm lane^2
    v = dpp_add<0x141>(v);    // row_half_mirror
    return dpp_add<0x140>(v); // row_mirror
}

// ---------------------------------------------------------------------------
// Prep: W1 [32][256] -> w1t bf16 [n][k=32]; W2 [256][256] -> w2t bf16 [n][k=256]
// (MFMA 16x16x32 B-frag needs k-contiguous rows per n). Coalesced reads over n.
// ---------------------------------------------------------------------------
__global__ __launch_bounds__(256) void prep_kernel(
    const float* __restrict__ W1, const float* __restrict__ W2,
    unsigned short* __restrict__ w1t, unsigned short* __restrict__ w2t)
{
    const int n = threadIdx.x;
    unsigned short tmp[8];
    if (blockIdx.x < 32) {
        const int k0 = blockIdx.x * 8;
        #pragma unroll
        for (int i = 0; i < 8; ++i) tmp[i] = f2bf(W2[(size_t)(k0+i)*HID_ + n]);
        *(bf16x8*)(w2t + (size_t)n*256 + k0) = *(const bf16x8*)tmp;
    } else {
        const int k0 = (blockIdx.x - 32) * 8;
        #pragma unroll
        for (int i = 0; i < 8; ++i) tmp[i] = f2bf(W1[(size_t)(k0+i)*HID_ + n]);
        *(bf16x8*)(w1t + (size_t)n*32 + k0) = *(const bf16x8*)tmp;
    }
}

// ---------------------------------------------------------------------------
// Fused actor. Block = (b, eighth of i): 16 query rows, 256 threads,
// grid 1024, LDS ~31 KB -> 4+ blocks/CU co-resident (latency hiding).
// Attention via MFMA (exact: all T=128 keys in LDS).
// Identities: softmax shift-invariance kills Kp[i]; sum w = 1 turns the
// Vp[i] term into a subtraction.
// ---------------------------------------------------------------------------
__global__ __launch_bounds__(256) void fused_actor_kernel(
    const float* __restrict__ state,
    const float* __restrict__ noise,
    const float* __restrict__ Wq, const float* __restrict__ Wk,
    const float* __restrict__ Wv,
    const unsigned short* __restrict__ w1t, const float* __restrict__ b1,
    const unsigned short* __restrict__ w2t, const float* __restrict__ b2,
    const float* __restrict__ Wmu, const float* __restrict__ bmu,
    const float* __restrict__ Wls, const float* __restrict__ bls,
    float* __restrict__ out)
{
    __shared__ float wq_s[K_*HK_], wk_s[K_*HK_], wv_s[K_*HK_]; // 2.25 KB
    __shared__ alignas(16) unsigned short Qb[16][HK_];       // 768 B
    __shared__ alignas(16) unsigned short Kb[H_][T_][8];     // 6 KB (row 16B)
    __shared__ alignas(16) unsigned short Vt[H_][K_][T_];    // 6 KB (row 256B)
    __shared__ alignas(16) float lsum[4][H_][16];            // 768 B
    __shared__ alignas(16) unsigned short a0b[16][40];       // 1.25 KB (row 80B)
    __shared__ union alignas(16) {
        unsigned short Pb[H_][16][PBS_];                     // 12.75 KB (row 272B)
        unsigned short x1s[16][264];                         // 8.25 KB
    } u;
    __shared__ alignas(16) float hp[4][16][4];               // 1 KB

    const int tid  = threadIdx.x;
    const int b    = blockIdx.x >> 3;
    const int iq   = blockIdx.x & 7;
    const int i0   = iq * 16;
    const int w    = tid >> 6;
    const int lq   = (tid >> 4) & 3;   // MFMA quad: k-chunk (A/B) / row-group (C/D)
    const int ln   = tid & 15;         // MFMA m (A) / n (B, C/D cols)
    const float* sb = state + (size_t)b*T_*K_;

    // ---- stage qkv weights ----
    if (tid < K_*HK_) { wq_s[tid]=Wq[tid]; wk_s[tid]=Wk[tid]; wv_s[tid]=Wv[tid]; }
    __syncthreads();

    // ---- projections: thread = (j, K-or-V) ----
    {
        const int j = tid >> 1, p = tid & 1;
        const float4 s0 = *(const float4*)(sb + j*8);
        const float4 s1 = *(const float4*)(sb + j*8 + 4);
        const float sv[8] = {s0.x,s0.y,s0.z,s0.w,s1.x,s1.y,s1.z,s1.w};
        const float* ws = p ? wv_s : wk_s;
        #pragma unroll
        for (int h = 0; h < H_; ++h) {
            unsigned short pk[8];
            #pragma unroll
            for (int k = 0; k < 8; ++k) {
                const int col = h*8 + k;
                float a = 0.f;
                #pragma unroll
                for (int m = 0; m < K_; ++m) a = fmaf(sv[m], ws[m*HK_+col], a);
                pk[k] = f2bf(a);
            }
            if (p == 0) {
                *(bf16x8*)&Kb[h][j][0] = *(const bf16x8*)pk;
            } else {
                #pragma unroll
                for (int d = 0; d < 8; ++d) Vt[h][d][j] = pk[d];  // transposed V
            }
        }
        // concat-state columns of a0b (block's own 16 rows), bf16-packed
        if (p == 0 && j >= i0 && j < i0 + 16) {
            unsigned short sb16[8];
            #pragma unroll
            for (int k = 0; k < 8; ++k) sb16[k] = f2bf(sv[k]);
            *(bf16x8*)&a0b[j - i0][HK_] = *(const bf16x8*)sb16;
        }
    }
    // ---- Q projection (bf16, pre-scaled 1/sqrt(8)): threads 0..127 ----
    if (tid < 128) {
        const int il = tid >> 3;
        const int c0 = (tid & 7) * 3;
        const float4 s0 = *(const float4*)(sb + (i0+il)*8);
        const float4 s1 = *(const float4*)(sb + (i0+il)*8 + 4);
        const float sv[8] = {s0.x,s0.y,s0.z,s0.w,s1.x,s1.y,s1.z,s1.w};
        #pragma unroll
        for (int cc = 0; cc < 3; ++cc) {
            const int col = c0 + cc;
            float aq = 0.f;
            #pragma unroll
            for (int m = 0; m < K_; ++m) aq = fmaf(sv[m], wq_s[m*HK_+col], aq);
            Qb[il][col] = f2bf(aq * 0.35355339059327373f);
        }
    }
    __syncthreads();

    // ---- S = Q@K^T via MFMA (K-dim 8 padded to 32 by lane-select zeros) ----
    // Wave w owns n-tiles {2w, 2w+1} (j in [32w,32w+32)); exp+mask in C-layout;
    // P -> LDS (bf16); per-wave row-sum partials via DPP red16 -> lsum[w].
    {
        const bf16x8 zf = {0,0,0,0,0,0,0,0};
        const f32x4 c0v = {0.f,0.f,0.f,0.f};
        float esum[H_][4];
        #pragma unroll
        for (int h = 0; h < H_; ++h)
            #pragma unroll
            for (int r = 0; r < 4; ++r) esum[h][r] = 0.f;
        #pragma unroll
        for (int h = 0; h < H_; ++h) {
            const bf16x8 tq = *(const bf16x8*)&Qb[ln][h*8];
            const bf16x8 qa = (lq == 0) ? tq : zf;
            #pragma unroll
            for (int nti = 0; nti < 2; ++nti) {
                const int nt = w*2 + nti;
                const bf16x8 tb = *(const bf16x8*)&Kb[h][nt*16 + ln][0];
                const bf16x8 kf = (lq == 0) ? tb : zf;
                f32x4 s = __builtin_amdgcn_mfma_f32_16x16x32_bf16(qa, kf, c0v, 0,0,0);
                #pragma unroll
                for (int r = 0; r < 4; ++r) {
                    const int il = lq*4 + r;
                    const int j  = nt*16 + ln;
                    const float e = (j == i0 + il) ? 0.f : __expf(s[r]);
                    esum[h][r] += e;
                    u.Pb[h][il][j] = f2bf(e);
                }
            }
        }
        #pragma unroll
        for (int h = 0; h < H_; ++h)
            #pragma unroll
            for (int r = 0; r < 4; ++r) {
                const float v = red16(esum[h][r]);
                if (ln == 0) lsum[w][h][lq*4 + r] = v;
            }
    }
    __syncthreads();

    // ---- X = P@V via MFMA (M=16, N=8 pad 16, K=128); epilogue: /l - Vp[i] ----
    if (w < H_) {
        const bf16x8 zf = {0,0,0,0,0,0,0,0};
        const int h = w;
        f32x4 x = {0.f,0.f,0.f,0.f};
        #pragma unroll
        for (int ks = 0; ks < 4; ++ks) {
            const int k0 = ks*32;
            const bf16x8 pa = *(const bf16x8*)&u.Pb[h][ln][k0 + lq*8];
            const bf16x8 tv = *(const bf16x8*)&Vt[h][ln & 7][k0 + lq*8];
            const bf16x8 vf = (ln < 8) ? tv : zf;
            x = __builtin_amdgcn_mfma_f32_16x16x32_bf16(pa, vf, x, 0, 0, 0);
        }
        if (ln < 8) {
            #pragma unroll
            for (int r = 0; r < 4; ++r) {
                const int il = lq*4 + r;
                const float l = lsum[0][h][il] + lsum[1][h][il]
                              + lsum[2][h][il] + lsum[3][h][il];
                const float xatt = x[r] / l - bf2f(Vt[h][ln][i0 + il]);
                a0b[il][h*8 + ln] = f2bf(xatt);
            }
        }
    }
    __syncthreads();   // a0b complete; Pb dead -> x1s may reuse union

    // ---- x1 = relu([x||state] @ W1 + b1) via MFMA, M=16, K=32 ----
    {
        const bf16x8 a0 = *(const bf16x8*)&a0b[ln][lq*8];
        #pragma unroll
        for (int nt = 0; nt < 4; ++nt) {
            const int n0 = (w*4 + nt)*16;
            const bf16x8 bf = *(const bf16x8*)(w1t + (size_t)(n0+ln)*32 + lq*8);
            const float bias = b1[n0+ln];
            f32x4 c = {bias, bias, bias, bias};
            f32x4 d = __builtin_amdgcn_mfma_f32_16x16x32_bf16(a0, bf, c, 0, 0, 0);
            #pragma unroll
            for (int r = 0; r < 4; ++r)
                u.x1s[lq*4 + r][n0+ln] = f2bf(fmaxf(d[r], 0.f));
        }
    }
    __syncthreads();

    // ---- x2 = relu(x1 @ W2 + b2) via MFMA: 4 N-tiles x 8 k-steps ----
    f32x4 acc2[4];
    #pragma unroll
    for (int nt = 0; nt < 4; ++nt) {
        const float bias = b2[(w*4+nt)*16 + ln];
        f32x4 c = {bias, bias, bias, bias};
        acc2[nt] = c;
    }
    #pragma unroll 2
    for (int ks = 0; ks < 8; ++ks) {
        const int k0 = ks*32;
        const bf16x8 a0 = *(const bf16x8*)&u.x1s[ln][k0 + lq*8];
        #pragma unroll
        for (int nt = 0; nt < 4; ++nt) {
            const bf16x8 bf = *(const bf16x8*)(w2t + (size_t)((w*4+nt)*16+ln)*256 + k0 + lq*8);
            acc2[nt] = __builtin_amdgcn_mfma_f32_16x16x32_bf16(a0, bf, acc2[nt], 0, 0, 0);
        }
    }

    // ---- heads: relu(x2).{Wmu,Wls}; DPP 16-lane reduce over n-lanes ----
    {
        float p[4][4];
        #pragma unroll
        for (int r = 0; r < 4; ++r)
            #pragma unroll
            for (int o = 0; o < 4; ++o) p[r][o] = 0.f;
        #pragma unroll
        for (int nt = 0; nt < 4; ++nt) {
            const int n = (w*4+nt)*16 + ln;
            const float2 wm = *(const float2*)(Wmu + n*OUT_);
            const float2 wl = *(const float2*)(Wls + n*OUT_);
            #pragma unroll
            for (int r = 0; r < 4; ++r) {
                const float x2 = fmaxf(acc2[nt][r], 0.f);
                p[r][0] = fmaf(x2, wm.x, p[r][0]);
                p[r][1] = fmaf(x2, wm.y, p[r][1]);
                p[r][2] = fmaf(x2, wl.x, p[r][2]);
                p[r][3] = fmaf(x2, wl.y, p[r][3]);
            }
        }
        #pragma unroll
        for (int r = 0; r < 4; ++r)
            #pragma unroll
            for (int o = 0; o < 4; ++o)
                p[r][o] = red16(p[r][o]);
        if (ln == 0) {
            #pragma unroll
            for (int r = 0; r < 4; ++r) {
                f32x4 pv = {p[r][0], p[r][1], p[r][2], p[r][3]};
                *(f32x4*)&hp[w][lq*4 + r][0] = pv;
            }
        }
    }
    __syncthreads();

    // ---- sampling tail: one thread per row ----
    if (tid < 16) {
        const int r = tid;
        const int grow = b*T_ + i0 + r;
        float pre[4];
        #pragma unroll
        for (int o = 0; o < 4; ++o)
            pre[o] = hp[0][r][o] + hp[1][r][o] + hp[2][r][o] + hp[3][r][o];
        float lp = 0.f;
        #pragma unroll
        for (int o = 0; o < OUT_; ++o) {
            float mu  = tanhf(pre[o]   + bmu[o]);
            float lsp = tanhf(pre[2+o] + bls[o]);
            float log_std = -20.f + 11.f * (lsp + 1.f);
            float sd = __expf(log_std);
            float n  = noise[(size_t)grow*OUT_ + o];
            float z  = fmaf(sd, n, mu);
            float a  = tanhf(z);
            out[(size_t)grow*OUT_ + o] = a;
            lp += -0.5f*n*n - log_std - 0.91893853320467274f
                  - logf(1.f - a*a + 1e-7f);
        }
        out[(size_t)B_*T_*OUT_ + grow] = lp;
    }
}

extern "C" void kernel_launch(void* const* d_in, const int* in_sizes, int n_in,
                              void* d_out, int out_size, void* d_ws, size_t ws_size,
                              hipStream_t stream)
{
    const float* state = (const float*)d_in[0];
    const float* noise = (const float*)d_in[1];
    const float* Wq  = (const float*)d_in[2];
    const float* Wk  = (const float*)d_in[3];
    const float* Wv  = (const float*)d_in[4];
    const float* W1  = (const float*)d_in[5];
    const float* b1  = (const float*)d_in[6];
    const float* W2  = (const float*)d_in[7];
    const float* b2  = (const float*)d_in[8];
    const float* Wmu = (const float*)d_in[9];
    const float* bmu = (const float*)d_in[10];
    const float* Wls = (const float*)d_in[11];
    const float* bls = (const float*)d_in[12];
    float* out = (float*)d_out;

    unsigned short* w1t = (unsigned short*)d_ws;       // 8192 bf16
    unsigned short* w2t = w1t + 8192;                  // 65536 bf16

    prep_kernel<<<dim3(36), dim3(256), 0, stream>>>(W1, W2, w1t, w2t);
    fused_actor_kernel<<<dim3(B_*8), dim3(256), 0, stream>>>(
        state, noise, Wq, Wk, Wv, w1t, b1, w2t, b2, Wmu, bmu, Wls, bls, out);
}

// Round 9
// 98.866 us; speedup vs baseline: 1.0406x; 1.0406x over previous
//
#include <hip/hip_runtime.h>
#include <math.h>

// Problem constants (RelTransformerActor)
namespace {
constexpr int B_  = 128;
constexpr int T_  = 128;
constexpr int K_  = 8;
constexpr int H_  = 3;
constexpr int HK_ = 24;
constexpr int HID_ = 256;
constexpr int OUT_ = 2;
constexpr int PBS_ = 144;  // Pb row stride (bf16): 288B = 16B-aligned, banks spread
}

typedef __attribute__((ext_vector_type(8))) short bf16x8;
typedef __attribute__((ext_vector_type(4))) float f32x4;

__device__ inline unsigned short f2bf(float x) {           // RNE fp32->bf16
    unsigned int u = __float_as_uint(x);
    u += 0x7FFFu + ((u >> 16) & 1u);
    return (unsigned short)(u >> 16);
}
__device__ inline float bf2f(unsigned short v) { return __uint_as_float((unsigned)v << 16); }

// Cross-lane add via DPP (VALU pipe, not DS).
template <int CTRL>
__device__ inline float dpp_add(float v) {
    int t = __builtin_amdgcn_update_dpp(0, __float_as_int(v), CTRL, 0xF, 0xF, true);
    return v + __int_as_float(t);
}
__device__ inline float red16(float v) {   // sum over 16-lane groups
    v = dpp_add<0xB1>(v);     // quad_perm lane^1
    v = dpp_add<0x4E>(v);     // quad_perm lane^2
    v = dpp_add<0x141>(v);    // row_half_mirror
    return dpp_add<0x140>(v); // row_mirror
}

// ---------------------------------------------------------------------------
// Prep: W1 [32][256] -> w1t bf16 [n][k=32]; W2 [256][256] -> w2t bf16 [n][k=256]
// (MFMA 16x16x32 B-frag needs k-contiguous rows per n). Coalesced reads over n.
// ---------------------------------------------------------------------------
__global__ __launch_bounds__(256) void prep_kernel(
    const float* __restrict__ W1, const float* __restrict__ W2,
    unsigned short* __restrict__ w1t, unsigned short* __restrict__ w2t)
{
    const int n = threadIdx.x;
    unsigned short tmp[8];
    if (blockIdx.x < 32) {
        const int k0 = blockIdx.x * 8;
        #pragma unroll
        for (int i = 0; i < 8; ++i) tmp[i] = f2bf(W2[(size_t)(k0+i)*HID_ + n]);
        *(bf16x8*)(w2t + (size_t)n*256 + k0) = *(const bf16x8*)tmp;
    } else {
        const int k0 = (blockIdx.x - 32) * 8;
        #pragma unroll
        for (int i = 0; i < 8; ++i) tmp[i] = f2bf(W1[(size_t)(k0+i)*HID_ + n]);
        *(bf16x8*)(w1t + (size_t)n*32 + k0) = *(const bf16x8*)tmp;
    }
}

// ---------------------------------------------------------------------------
// Fused actor. Block = (b, quarter of i): 32 query rows, 256 threads,
// grid 512 = 2 blocks/CU (grid-capped -> 2 waves/SIMD, so up to 256 VGPR).
// ALL weight fragments (W1/W2/biases/head weights) are prefetched into
// registers at kernel start: their global-load latency overlaps proj/S/PV
// instead of serializing inside the x1/x2 stages.
// Attention via MFMA (exact: all T=128 keys in LDS). Identities: softmax
// shift-invariance kills Kp[i]; sum w = 1 turns Vp[i] into a subtraction.
// ---------------------------------------------------------------------------
__global__ __launch_bounds__(256, 2) void fused_actor_kernel(
    const float* __restrict__ state,
    const float* __restrict__ noise,
    const float* __restrict__ Wq, const float* __restrict__ Wk,
    const float* __restrict__ Wv,
    const unsigned short* __restrict__ w1t, const float* __restrict__ b1,
    const unsigned short* __restrict__ w2t, const float* __restrict__ b2,
    const float* __restrict__ Wmu, const float* __restrict__ bmu,
    const float* __restrict__ Wls, const float* __restrict__ bls,
    float* __restrict__ out)
{
    __shared__ float wq_s[K_*HK_], wk_s[K_*HK_], wv_s[K_*HK_]; // 2.25 KB
    __shared__ alignas(16) unsigned short Qb[32][HK_];       // 1.5 KB (row 48B)
    __shared__ alignas(16) unsigned short Kb[H_][T_][8];     // 6 KB (row 16B)
    __shared__ alignas(16) unsigned short Vt[H_][K_][T_];    // 6 KB (row 256B)
    __shared__ alignas(16) float lsum[4][H_][32];            // 1.5 KB
    __shared__ alignas(16) unsigned short a0b[32][40];       // 2.5 KB (row 80B)
    __shared__ union alignas(16) {
        unsigned short Pb[H_][32][PBS_];                     // 27 KB (row 288B)
        unsigned short x1s[32][264];                         // 16.5 KB
    } u;
    __shared__ alignas(16) float hp[4][32][4];               // 2 KB

    const int tid  = threadIdx.x;
    const int b    = blockIdx.x >> 2;
    const int iq   = blockIdx.x & 3;
    const int i0   = iq * 32;
    const int w    = tid >> 6;
    const int lq   = (tid >> 4) & 3;   // MFMA quad: k-chunk (A/B) / row-group (C/D)
    const int ln   = tid & 15;         // MFMA m (A) / n (B, C/D cols)
    const float* sb = state + (size_t)b*T_*K_;

    // ---- LDS staging issue first (barrier 1 waits on it) ----
    if (tid < K_*HK_) { wq_s[tid]=Wq[tid]; wk_s[tid]=Wk[tid]; wv_s[tid]=Wv[tid]; }

    // ---- REGISTER PREFETCH: independent of all stages; latency overlaps
    //      proj/S/PV. 32 W2-frags (128 VGPR) + 4 W1-frags + biases + heads.
    bf16x8 w2f[8][4];
    #pragma unroll
    for (int ks = 0; ks < 8; ++ks)
        #pragma unroll
        for (int nt = 0; nt < 4; ++nt)
            w2f[ks][nt] = *(const bf16x8*)(w2t + (size_t)((w*4+nt)*16+ln)*256 + ks*32 + lq*8);
    bf16x8 w1f[4];
    float b1v[4], b2v[4];
    float2 wmv[4], wlv[4];
    #pragma unroll
    for (int nt = 0; nt < 4; ++nt) {
        const int n0 = (w*4 + nt)*16 + ln;
        w1f[nt] = *(const bf16x8*)(w1t + (size_t)n0*32 + lq*8);
        b1v[nt] = b1[n0];
        b2v[nt] = b2[n0];
        wmv[nt] = *(const float2*)(Wmu + n0*OUT_);
        wlv[nt] = *(const float2*)(Wls + n0*OUT_);
    }
    __syncthreads();

    // ---- projections: thread = (j, K-or-V) ----
    {
        const int j = tid >> 1, p = tid & 1;
        const float4 s0 = *(const float4*)(sb + j*8);
        const float4 s1 = *(const float4*)(sb + j*8 + 4);
        const float sv[8] = {s0.x,s0.y,s0.z,s0.w,s1.x,s1.y,s1.z,s1.w};
        const float* ws = p ? wv_s : wk_s;
        #pragma unroll
        for (int h = 0; h < H_; ++h) {
            unsigned short pk[8];
            #pragma unroll
            for (int k = 0; k < 8; ++k) {
                const int col = h*8 + k;
                float a = 0.f;
                #pragma unroll
                for (int m = 0; m < K_; ++m) a = fmaf(sv[m], ws[m*HK_+col], a);
                pk[k] = f2bf(a);
            }
            if (p == 0) {
                *(bf16x8*)&Kb[h][j][0] = *(const bf16x8*)pk;
            } else {
                #pragma unroll
                for (int d = 0; d < 8; ++d) Vt[h][d][j] = pk[d];  // transposed V
            }
        }
        // concat-state columns of a0b (block's own 32 rows), bf16-packed
        if (p == 0 && j >= i0 && j < i0 + 32) {
            unsigned short sb16[8];
            #pragma unroll
            for (int k = 0; k < 8; ++k) sb16[k] = f2bf(sv[k]);
            *(bf16x8*)&a0b[j - i0][HK_] = *(const bf16x8*)sb16;
        }
    }
    // ---- Q projection (bf16, pre-scaled 1/sqrt(8)): 3 cols per thread ----
    {
        const int il = tid >> 3;
        const int c0 = (tid & 7) * 3;
        const float4 s0 = *(const float4*)(sb + (i0+il)*8);
        const float4 s1 = *(const float4*)(sb + (i0+il)*8 + 4);
        const float sv[8] = {s0.x,s0.y,s0.z,s0.w,s1.x,s1.y,s1.z,s1.w};
        #pragma unroll
        for (int cc = 0; cc < 3; ++cc) {
            const int col = c0 + cc;
            float aq = 0.f;
            #pragma unroll
            for (int m = 0; m < K_; ++m) aq = fmaf(sv[m], wq_s[m*HK_+col], aq);
            Qb[il][col] = f2bf(aq * 0.35355339059327373f);
        }
    }
    __syncthreads();

    // ---- S = Q@K^T via MFMA (K-dim 8 padded to 32 by lane-select zeros) ----
    {
        const bf16x8 zf = {0,0,0,0,0,0,0,0};
        const f32x4 c0v = {0.f,0.f,0.f,0.f};
        float esum[H_][2][4];
        #pragma unroll
        for (int h = 0; h < H_; ++h)
            #pragma unroll
            for (int mt = 0; mt < 2; ++mt)
                #pragma unroll
                for (int r = 0; r < 4; ++r) esum[h][mt][r] = 0.f;
        #pragma unroll
        for (int h = 0; h < H_; ++h) {
            bf16x8 qa[2];
            #pragma unroll
            for (int mt = 0; mt < 2; ++mt) {
                const bf16x8 t = *(const bf16x8*)&Qb[mt*16 + ln][h*8];
                qa[mt] = (lq == 0) ? t : zf;
            }
            #pragma unroll
            for (int nti = 0; nti < 2; ++nti) {
                const int nt = w*2 + nti;
                const bf16x8 tb = *(const bf16x8*)&Kb[h][nt*16 + ln][0];
                const bf16x8 kf = (lq == 0) ? tb : zf;
                #pragma unroll
                for (int mt = 0; mt < 2; ++mt) {
                    f32x4 s = __builtin_amdgcn_mfma_f32_16x16x32_bf16(qa[mt], kf, c0v, 0,0,0);
                    #pragma unroll
                    for (int r = 0; r < 4; ++r) {
                        const int il = mt*16 + lq*4 + r;
                        const int j  = nt*16 + ln;
                        const float e = (j == i0 + il) ? 0.f : __expf(s[r]);
                        esum[h][mt][r] += e;
                        u.Pb[h][il][j] = f2bf(e);
                    }
                }
            }
        }
        #pragma unroll
        for (int h = 0; h < H_; ++h)
            #pragma unroll
            for (int mt = 0; mt < 2; ++mt)
                #pragma unroll
                for (int r = 0; r < 4; ++r) {
                    const float v = red16(esum[h][mt][r]);
                    if (ln == 0) lsum[w][h][mt*16 + lq*4 + r] = v;
                }
    }
    __syncthreads();

    // ---- X = P@V via MFMA (M=32, N=8 pad 16, K=128); epilogue: /l - Vp[i] ----
    {
        const bf16x8 zf = {0,0,0,0,0,0,0,0};
        for (int id = w; id < 6; id += 4) {          // item = (h, m-tile)
            const int h = id >> 1, mt = id & 1;
            f32x4 x = {0.f,0.f,0.f,0.f};
            #pragma unroll
            for (int ks = 0; ks < 4; ++ks) {
                const int k0 = ks*32;
                const bf16x8 pa = *(const bf16x8*)&u.Pb[h][mt*16 + ln][k0 + lq*8];
                const bf16x8 tv = *(const bf16x8*)&Vt[h][ln & 7][k0 + lq*8];
                const bf16x8 vf = (ln < 8) ? tv : zf;
                x = __builtin_amdgcn_mfma_f32_16x16x32_bf16(pa, vf, x, 0, 0, 0);
            }
            if (ln < 8) {
                #pragma unroll
                for (int r = 0; r < 4; ++r) {
                    const int il = mt*16 + lq*4 + r;
                    const float l = lsum[0][h][il] + lsum[1][h][il]
                                  + lsum[2][h][il] + lsum[3][h][il];
                    const float xatt = x[r] / l - bf2f(Vt[h][ln][i0 + il]);
                    a0b[il][h*8 + ln] = f2bf(xatt);
                }
            }
        }
    }
    __syncthreads();   // a0b complete; Pb dead -> x1s may reuse union

    // ---- x1 = relu([x||state] @ W1 + b1) via MFMA, M=32 (2 tiles), K=32 ----
    {
        const bf16x8 a0 = *(const bf16x8*)&a0b[ln][lq*8];
        const bf16x8 a1 = *(const bf16x8*)&a0b[16+ln][lq*8];
        #pragma unroll
        for (int nt = 0; nt < 4; ++nt) {
            const int n0 = (w*4 + nt)*16;
            const float bias = b1v[nt];
            f32x4 c = {bias, bias, bias, bias};
            f32x4 d0 = __builtin_amdgcn_mfma_f32_16x16x32_bf16(a0, w1f[nt], c, 0, 0, 0);
            f32x4 d1 = __builtin_amdgcn_mfma_f32_16x16x32_bf16(a1, w1f[nt], c, 0, 0, 0);
            #pragma unroll
            for (int r = 0; r < 4; ++r) {
                u.x1s[lq*4 + r][n0+ln]      = f2bf(fmaxf(d0[r], 0.f));
                u.x1s[16 + lq*4 + r][n0+ln] = f2bf(fmaxf(d1[r], 0.f));
            }
        }
    }
    __syncthreads();

    // ---- x2 = relu(x1 @ W2 + b2) via MFMA: 2 M x 4 N x 8 k, B-frags in regs ----
    f32x4 acc2[2][4];
    #pragma unroll
    for (int nt = 0; nt < 4; ++nt) {
        const float bias = b2v[nt];
        f32x4 c = {bias, bias, bias, bias};
        acc2[0][nt] = c; acc2[1][nt] = c;
    }
    #pragma unroll
    for (int ks = 0; ks < 8; ++ks) {
        const int k0 = ks*32;
        const bf16x8 a0 = *(const bf16x8*)&u.x1s[ln][k0 + lq*8];
        const bf16x8 a1 = *(const bf16x8*)&u.x1s[16+ln][k0 + lq*8];
        #pragma unroll
        for (int nt = 0; nt < 4; ++nt) {
            acc2[0][nt] = __builtin_amdgcn_mfma_f32_16x16x32_bf16(a0, w2f[ks][nt], acc2[0][nt], 0,0,0);
            acc2[1][nt] = __builtin_amdgcn_mfma_f32_16x16x32_bf16(a1, w2f[ks][nt], acc2[1][nt], 0,0,0);
        }
    }

    // ---- heads: relu(x2).{Wmu,Wls}; DPP 16-lane reduce over n-lanes ----
    {
        float p[2][4][4];
        #pragma unroll
        for (int mt = 0; mt < 2; ++mt)
            #pragma unroll
            for (int r = 0; r < 4; ++r)
                #pragma unroll
                for (int o = 0; o < 4; ++o) p[mt][r][o] = 0.f;
        #pragma unroll
        for (int nt = 0; nt < 4; ++nt) {
            const float2 wm = wmv[nt];
            const float2 wl = wlv[nt];
            #pragma unroll
            for (int mt = 0; mt < 2; ++mt) {
                #pragma unroll
                for (int r = 0; r < 4; ++r) {
                    const float x2 = fmaxf(acc2[mt][nt][r], 0.f);
                    p[mt][r][0] = fmaf(x2, wm.x, p[mt][r][0]);
                    p[mt][r][1] = fmaf(x2, wm.y, p[mt][r][1]);
                    p[mt][r][2] = fmaf(x2, wl.x, p[mt][r][2]);
                    p[mt][r][3] = fmaf(x2, wl.y, p[mt][r][3]);
                }
            }
        }
        #pragma unroll
        for (int mt = 0; mt < 2; ++mt)
            #pragma unroll
            for (int r = 0; r < 4; ++r)
                #pragma unroll
                for (int o = 0; o < 4; ++o)
                    p[mt][r][o] = red16(p[mt][r][o]);
        if (ln == 0) {
            #pragma unroll
            for (int mt = 0; mt < 2; ++mt)
                #pragma unroll
                for (int r = 0; r < 4; ++r) {
                    f32x4 pv = {p[mt][r][0], p[mt][r][1], p[mt][r][2], p[mt][r][3]};
                    *(f32x4*)&hp[w][mt*16 + lq*4 + r][0] = pv;
                }
        }
    }
    __syncthreads();

    // ---- sampling tail: one thread per row ----
    if (tid < 32) {
        const int r = tid;
        const int grow = b*T_ + i0 + r;
        float pre[4];
        #pragma unroll
        for (int o = 0; o < 4; ++o)
            pre[o] = hp[0][r][o] + hp[1][r][o] + hp[2][r][o] + hp[3][r][o];
        float lp = 0.f;
        #pragma unroll
        for (int o = 0; o < OUT_; ++o) {
            float mu  = tanhf(pre[o]   + bmu[o]);
            float lsp = tanhf(pre[2+o] + bls[o]);
            float log_std = -20.f + 11.f * (lsp + 1.f);
            float sd = __expf(log_std);
            float n  = noise[(size_t)grow*OUT_ + o];
            float z  = fmaf(sd, n, mu);
            float a  = tanhf(z);
            out[(size_t)grow*OUT_ + o] = a;
            lp += -0.5f*n*n - log_std - 0.91893853320467274f
                  - logf(1.f - a*a + 1e-7f);
        }
        out[(size_t)B_*T_*OUT_ + grow] = lp;
    }
}

extern "C" void kernel_launch(void* const* d_in, const int* in_sizes, int n_in,
                              void* d_out, int out_size, void* d_ws, size_t ws_size,
                              hipStream_t stream)
{
    const float* state = (const float*)d_in[0];
    const float* noise = (const float*)d_in[1];
    const float* Wq  = (const float*)d_in[2];
    const float* Wk  = (const float*)d_in[3];
    const float* Wv  = (const float*)d_in[4];
    const float* W1  = (const float*)d_in[5];
    const float* b1  = (const float*)d_in[6];
    const float* W2  = (const float*)d_in[7];
    const float* b2  = (const float*)d_in[8];
    const float* Wmu = (const float*)d_in[9];
    const float* bmu = (const float*)d_in[10];
    const float* Wls = (const float*)d_in[11];
    const float* bls = (const float*)d_in[12];
    float* out = (float*)d_out;

    unsigned short* w1t = (unsigned short*)d_ws;       // 8192 bf16
    unsigned short* w2t = w1t + 8192;                  // 65536 bf16

    prep_kernel<<<dim3(36), dim3(256), 0, stream>>>(W1, W2, w1t, w2t);
    fused_actor_kernel<<<dim3(B_*4), dim3(256), 0, stream>>>(
        state, noise, Wq, Wk, Wv, w1t, b1, w2t, b2, Wmu, bmu, Wls, bls, out);
}

// Round 10
// 95.697 us; speedup vs baseline: 1.0751x; 1.0331x over previous
//
#include <hip/hip_runtime.h>
#include <math.h>

// Problem constants (RelTransformerActor)
namespace {
constexpr int B_  = 128;
constexpr int T_  = 128;
constexpr int K_  = 8;
constexpr int H_  = 3;
constexpr int HK_ = 24;
constexpr int HID_ = 256;
constexpr int OUT_ = 2;
constexpr int PBS_ = 136;  // P row stride (bf16): 272B, 16B-aligned, banks spread
constexpr int X1S_ = 264;  // x1 row stride (bf16): 528B
}

typedef __attribute__((ext_vector_type(8))) short bf16x8;
typedef __attribute__((ext_vector_type(4))) float f32x4;

__device__ inline unsigned short f2bf(float x) {           // RNE fp32->bf16
    unsigned int u = __float_as_uint(x);
    u += 0x7FFFu + ((u >> 16) & 1u);
    return (unsigned short)(u >> 16);
}
__device__ inline float bf2f(unsigned short v) { return __uint_as_float((unsigned)v << 16); }

// Cross-lane add via DPP (VALU pipe, not DS).
template <int CTRL>
__device__ inline float dpp_add(float v) {
    int t = __builtin_amdgcn_update_dpp(0, __float_as_int(v), CTRL, 0xF, 0xF, true);
    return v + __int_as_float(t);
}
__device__ inline float red16(float v) {   // sum over 16-lane groups
    v = dpp_add<0xB1>(v);     // quad_perm lane^1
    v = dpp_add<0x4E>(v);     // quad_perm lane^2
    v = dpp_add<0x141>(v);    // row_half_mirror
    return dpp_add<0x140>(v); // row_mirror
}

// ---------------------------------------------------------------------------
// Prep: W1 [32][256] -> w1t bf16 [n][k=32]; W2 [256][256] -> w2t bf16 [n][k=256]
// (MFMA 16x16x32 B-frag needs k-contiguous rows per n). Coalesced reads over n.
// ---------------------------------------------------------------------------
__global__ __launch_bounds__(256) void prep_kernel(
    const float* __restrict__ W1, const float* __restrict__ W2,
    unsigned short* __restrict__ w1t, unsigned short* __restrict__ w2t)
{
    const int n = threadIdx.x;
    unsigned short tmp[8];
    if (blockIdx.x < 32) {
        const int k0 = blockIdx.x * 8;
        #pragma unroll
        for (int i = 0; i < 8; ++i) tmp[i] = f2bf(W2[(size_t)(k0+i)*HID_ + n]);
        *(bf16x8*)(w2t + (size_t)n*256 + k0) = *(const bf16x8*)tmp;
    } else {
        const int k0 = (blockIdx.x - 32) * 8;
        #pragma unroll
        for (int i = 0; i < 8; ++i) tmp[i] = f2bf(W1[(size_t)(k0+i)*HID_ + n]);
        *(bf16x8*)(w1t + (size_t)n*32 + k0) = *(const bf16x8*)tmp;
    }
}

// ---------------------------------------------------------------------------
// Fused actor, wave-independent restructure. Block = (b, half of T): 64 rows,
// 256 threads, grid 256 = 1 block/CU (4 waves/CU -> ~512 VGPR budget, so
// weight prefetch is free). Wave w owns rows [w*16, w*16+16) END-TO-END from
// S through x1 with NO __syncthreads (wave-private LDS arena; lgkmcnt only).
// Barriers: stage-weights, proj, x1->x2, heads->tail  (4 total, was 6).
// Identities: softmax shift-invariance kills Kp[i]; sum w = 1 turns Vp[i]
// into a subtraction.
// ---------------------------------------------------------------------------
__global__ __launch_bounds__(256, 1) void fused_actor_kernel(
    const float* __restrict__ state,
    const float* __restrict__ noise,
    const float* __restrict__ Wq, const float* __restrict__ Wk,
    const float* __restrict__ Wv,
    const unsigned short* __restrict__ w1t, const float* __restrict__ b1,
    const unsigned short* __restrict__ w2t, const float* __restrict__ b2,
    const float* __restrict__ Wmu, const float* __restrict__ bmu,
    const float* __restrict__ Wls, const float* __restrict__ bls,
    float* __restrict__ out)
{
    __shared__ float wq_s[K_*HK_], wk_s[K_*HK_], wv_s[K_*HK_]; // 2.25 KB
    __shared__ alignas(16) unsigned short Qb[64][HK_];       // 3 KB (row 48B)
    __shared__ alignas(16) unsigned short Kb[H_][T_][8];     // 6 KB (row 16B)
    __shared__ alignas(16) unsigned short Vt[H_][K_][T_];    // 6 KB (row 256B)
    __shared__ alignas(16) float lsw[4][H_][16];             // 768 B
    __shared__ alignas(16) unsigned short a0b[64][40];       // 5 KB (row 80B)
    __shared__ union alignas(16) Arena {                     // per-wave arena
        unsigned short P[16][PBS_];                          // 4.25 KB
        unsigned short x1[16][X1S_];                         // 8.25 KB
    } arena[4];                                              // 33 KB
    __shared__ alignas(16) float hp[4][64][4];               // 4 KB

    const int tid  = threadIdx.x;
    const int b    = blockIdx.x >> 1;
    const int i0   = (blockIdx.x & 1) * 64;      // 64-row slice of T
    const int w    = tid >> 6;
    const int lq   = (tid >> 4) & 3;   // MFMA quad: k-chunk (A/B) / row-group (C/D)
    const int ln   = tid & 15;         // MFMA m (A) / n (B, C/D cols)
    const float* sb = state + (size_t)b*T_*K_;

    // ---- stage qkv weights ----
    if (tid < K_*HK_) { wq_s[tid]=Wq[tid]; wk_s[tid]=Wk[tid]; wv_s[tid]=Wv[tid]; }

    // ---- weight/bias prefetch (free at 1 wave/SIMD; overlaps attention) ----
    bf16x8 w2f[8][4];                  // wave's x2 B-frags: n-slice w*64..+64
    #pragma unroll
    for (int ks = 0; ks < 8; ++ks)
        #pragma unroll
        for (int nt = 0; nt < 4; ++nt)
            w2f[ks][nt] = *(const bf16x8*)(w2t + (size_t)((w*4+nt)*16+ln)*256 + ks*32 + lq*8);
    bf16x8 w1f[16];                    // x1 B-frags: full N=256
    #pragma unroll
    for (int nt = 0; nt < 16; ++nt)
        w1f[nt] = *(const bf16x8*)(w1t + (size_t)(nt*16+ln)*32 + lq*8);
    float b1v[16];
    #pragma unroll
    for (int nt = 0; nt < 16; ++nt) b1v[nt] = b1[nt*16 + ln];
    float b2v[4];
    float2 wmv[4], wlv[4];
    #pragma unroll
    for (int nt = 0; nt < 4; ++nt) {
        const int n0 = (w*4 + nt)*16 + ln;
        b2v[nt] = b2[n0];
        wmv[nt] = *(const float2*)(Wmu + n0*OUT_);
        wlv[nt] = *(const float2*)(Wls + n0*OUT_);
    }
    __syncthreads();                                   // barrier 1

    // ---- projections (cooperative): thread = (j, K-or-V) ----
    {
        const int j = tid >> 1, p = tid & 1;
        const float4 s0 = *(const float4*)(sb + j*8);
        const float4 s1 = *(const float4*)(sb + j*8 + 4);
        const float sv[8] = {s0.x,s0.y,s0.z,s0.w,s1.x,s1.y,s1.z,s1.w};
        const float* ws = p ? wv_s : wk_s;
        #pragma unroll
        for (int h = 0; h < H_; ++h) {
            unsigned short pk[8];
            #pragma unroll
            for (int k = 0; k < 8; ++k) {
                const int col = h*8 + k;
                float a = 0.f;
                #pragma unroll
                for (int m = 0; m < K_; ++m) a = fmaf(sv[m], ws[m*HK_+col], a);
                pk[k] = f2bf(a);
            }
            if (p == 0) {
                *(bf16x8*)&Kb[h][j][0] = *(const bf16x8*)pk;
            } else {
                #pragma unroll
                for (int d = 0; d < 8; ++d) Vt[h][d][j] = pk[d];  // transposed V
            }
        }
        // concat-state columns of a0b (block's 64 rows), bf16-packed
        if (p == 0 && j >= i0 && j < i0 + 64) {
            unsigned short sb16[8];
            #pragma unroll
            for (int k = 0; k < 8; ++k) sb16[k] = f2bf(sv[k]);
            *(bf16x8*)&a0b[j - i0][HK_] = *(const bf16x8*)sb16;
        }
    }
    // ---- Q projection (bf16, pre-scaled 1/sqrt(8)): 6 cols of one row ----
    {
        const int il = tid >> 2;               // 0..63
        const int c0 = (tid & 3) * 6;
        const float4 s0 = *(const float4*)(sb + (i0+il)*8);
        const float4 s1 = *(const float4*)(sb + (i0+il)*8 + 4);
        const float sv[8] = {s0.x,s0.y,s0.z,s0.w,s1.x,s1.y,s1.z,s1.w};
        #pragma unroll
        for (int cc = 0; cc < 6; ++cc) {
            const int col = c0 + cc;
            float aq = 0.f;
            #pragma unroll
            for (int m = 0; m < K_; ++m) aq = fmaf(sv[m], wq_s[m*HK_+col], aq);
            Qb[il][col] = f2bf(aq * 0.35355339059327373f);
        }
    }
    __syncthreads();                                   // barrier 2

    // ================= wave-private phase: rows r0..r0+16 =================
    const int rw = w*16;                   // block-local first row of wave
    Arena* ar = &arena[w];

    // ---- S = Q@K^T (24 MFMAs), exp+mask, P->arena, row-sums via DPP ----
    {
        const bf16x8 zf = {0,0,0,0,0,0,0,0};
        const f32x4 c0v = {0.f,0.f,0.f,0.f};
        float esum[H_][4];
        #pragma unroll
        for (int h = 0; h < H_; ++h)
            #pragma unroll
            for (int r = 0; r < 4; ++r) esum[h][r] = 0.f;
        #pragma unroll
        for (int h = 0; h < H_; ++h) {
            const bf16x8 tq = *(const bf16x8*)&Qb[rw + ln][h*8];
            const bf16x8 qa = (lq == 0) ? tq : zf;
            #pragma unroll
            for (int nt = 0; nt < 8; ++nt) {
                const bf16x8 tb = *(const bf16x8*)&Kb[h][nt*16 + ln][0];
                const bf16x8 kf = (lq == 0) ? tb : zf;
                f32x4 s = __builtin_amdgcn_mfma_f32_16x16x32_bf16(qa, kf, c0v, 0,0,0);
                #pragma unroll
                for (int r = 0; r < 4; ++r) {
                    const int rl = lq*4 + r;             // row within wave tile
                    const int j  = nt*16 + ln;
                    const float e = (j == i0 + rw + rl) ? 0.f : __expf(s[r]);
                    esum[h][r] += e;
                    ar->P[rl][j] = f2bf(e);
                }
            }
        }
        #pragma unroll
        for (int h = 0; h < H_; ++h)
            #pragma unroll
            for (int r = 0; r < 4; ++r) {
                const float v = red16(esum[h][r]);
                if (ln == 0) lsw[w][h][lq*4 + r] = v;
            }
    }
    // (no __syncthreads: same-wave LDS RAW, compiler orders via lgkmcnt)

    // ---- X = P@V (12 MFMAs); epilogue: /l - Vp[i] -> a0b ----
    {
        const bf16x8 zf = {0,0,0,0,0,0,0,0};
        #pragma unroll
        for (int h = 0; h < H_; ++h) {
            f32x4 x = {0.f,0.f,0.f,0.f};
            #pragma unroll
            for (int ks = 0; ks < 4; ++ks) {
                const bf16x8 pa = *(const bf16x8*)&ar->P[ln][ks*32 + lq*8];
                const bf16x8 tv = *(const bf16x8*)&Vt[h][ln & 7][ks*32 + lq*8];
                const bf16x8 vf = (ln < 8) ? tv : zf;
                x = __builtin_amdgcn_mfma_f32_16x16x32_bf16(pa, vf, x, 0, 0, 0);
            }
            if (ln < 8) {
                #pragma unroll
                for (int r = 0; r < 4; ++r) {
                    const int rl = lq*4 + r;
                    const float l = lsw[w][h][rl];
                    const float xatt = x[r] / l - bf2f(Vt[h][ln][i0 + rw + rl]);
                    a0b[rw + rl][h*8 + ln] = f2bf(xatt);
                }
            }
        }
    }

    // ---- x1 = relu([x||state] @ W1 + b1): 16 MFMAs, full N=256 ----
    {
        const bf16x8 a0 = *(const bf16x8*)&a0b[rw + ln][lq*8];   // P dead; arena reused
        #pragma unroll
        for (int nt = 0; nt < 16; ++nt) {
            const float bias = b1v[nt];
            f32x4 c = {bias, bias, bias, bias};
            f32x4 d = __builtin_amdgcn_mfma_f32_16x16x32_bf16(a0, w1f[nt], c, 0, 0, 0);
            #pragma unroll
            for (int r = 0; r < 4; ++r)
                ar->x1[lq*4 + r][nt*16 + ln] = f2bf(fmaxf(d[r], 0.f));
        }
    }
    __syncthreads();                                   // barrier 3

    // ---- x2 = relu(x1 @ W2 + b2): M=64 (4 m-tiles), wave's N=64 slice ----
    f32x4 acc2[4][4];                      // [mt][nt]
    #pragma unroll
    for (int nt = 0; nt < 4; ++nt) {
        const float bias = b2v[nt];
        f32x4 c = {bias, bias, bias, bias};
        #pragma unroll
        for (int mt = 0; mt < 4; ++mt) acc2[mt][nt] = c;
    }
    #pragma unroll
    for (int ks = 0; ks < 8; ++ks) {
        bf16x8 a[4];
        #pragma unroll
        for (int mt = 0; mt < 4; ++mt)
            a[mt] = *(const bf16x8*)&arena[mt].x1[ln][ks*32 + lq*8];
        #pragma unroll
        for (int nt = 0; nt < 4; ++nt)
            #pragma unroll
            for (int mt = 0; mt < 4; ++mt)
                acc2[mt][nt] = __builtin_amdgcn_mfma_f32_16x16x32_bf16(a[mt], w2f[ks][nt], acc2[mt][nt], 0,0,0);
    }

    // ---- heads: relu(x2).{Wmu,Wls}; DPP 16-lane reduce over n-lanes ----
    {
        float p[4][4][4];                  // [mt][r][o]
        #pragma unroll
        for (int mt = 0; mt < 4; ++mt)
            #pragma unroll
            for (int r = 0; r < 4; ++r)
                #pragma unroll
                for (int o = 0; o < 4; ++o) p[mt][r][o] = 0.f;
        #pragma unroll
        for (int nt = 0; nt < 4; ++nt) {
            const float2 wm = wmv[nt];
            const float2 wl = wlv[nt];
            #pragma unroll
            for (int mt = 0; mt < 4; ++mt) {
                #pragma unroll
                for (int r = 0; r < 4; ++r) {
                    const float x2 = fmaxf(acc2[mt][nt][r], 0.f);
                    p[mt][r][0] = fmaf(x2, wm.x, p[mt][r][0]);
                    p[mt][r][1] = fmaf(x2, wm.y, p[mt][r][1]);
                    p[mt][r][2] = fmaf(x2, wl.x, p[mt][r][2]);
                    p[mt][r][3] = fmaf(x2, wl.y, p[mt][r][3]);
                }
            }
        }
        #pragma unroll
        for (int mt = 0; mt < 4; ++mt)
            #pragma unroll
            for (int r = 0; r < 4; ++r)
                #pragma unroll
                for (int o = 0; o < 4; ++o)
                    p[mt][r][o] = red16(p[mt][r][o]);
        if (ln == 0) {
            #pragma unroll
            for (int mt = 0; mt < 4; ++mt)
                #pragma unroll
                for (int r = 0; r < 4; ++r) {
                    f32x4 pv = {p[mt][r][0], p[mt][r][1], p[mt][r][2], p[mt][r][3]};
                    *(f32x4*)&hp[w][mt*16 + lq*4 + r][0] = pv;
                }
        }
    }
    __syncthreads();                                   // barrier 4

    // ---- sampling tail: one thread per row ----
    if (tid < 64) {
        const int r = tid;
        const int grow = b*T_ + i0 + r;
        float pre[4];
        #pragma unroll
        for (int o = 0; o < 4; ++o)
            pre[o] = hp[0][r][o] + hp[1][r][o] + hp[2][r][o] + hp[3][r][o];
        float lp = 0.f;
        #pragma unroll
        for (int o = 0; o < OUT_; ++o) {
            float mu  = tanhf(pre[o]   + bmu[o]);
            float lsp = tanhf(pre[2+o] + bls[o]);
            float log_std = -20.f + 11.f * (lsp + 1.f);
            float sd = __expf(log_std);
            float n  = noise[(size_t)grow*OUT_ + o];
            float z  = fmaf(sd, n, mu);
            float a  = tanhf(z);
            out[(size_t)grow*OUT_ + o] = a;
            lp += -0.5f*n*n - log_std - 0.91893853320467274f
                  - logf(1.f - a*a + 1e-7f);
        }
        out[(size_t)B_*T_*OUT_ + grow] = lp;
    }
}

extern "C" void kernel_launch(void* const* d_in, const int* in_sizes, int n_in,
                              void* d_out, int out_size, void* d_ws, size_t ws_size,
                              hipStream_t stream)
{
    const float* state = (const float*)d_in[0];
    const float* noise = (const float*)d_in[1];
    const float* Wq  = (const float*)d_in[2];
    const float* Wk  = (const float*)d_in[3];
    const float* Wv  = (const float*)d_in[4];
    const float* W1  = (const float*)d_in[5];
    const float* b1  = (const float*)d_in[6];
    const float* W2  = (const float*)d_in[7];
    const float* b2  = (const float*)d_in[8];
    const float* Wmu = (const float*)d_in[9];
    const float* bmu = (const float*)d_in[10];
    const float* Wls = (const float*)d_in[11];
    const float* bls = (const float*)d_in[12];
    float* out = (float*)d_out;

    unsigned short* w1t = (unsigned short*)d_ws;       // 8192 bf16
    unsigned short* w2t = w1t + 8192;                  // 65536 bf16

    prep_kernel<<<dim3(36), dim3(256), 0, stream>>>(W1, W2, w1t, w2t);
    fused_actor_kernel<<<dim3(B_*2), dim3(256), 0, stream>>>(
        state, noise, Wq, Wk, Wv, w1t, b1, w2t, b2, Wmu, bmu, Wls, bls, out);
}

// Round 11
// 92.789 us; speedup vs baseline: 1.1088x; 1.0313x over previous
//
#include <hip/hip_runtime.h>
#include <math.h>

// Problem constants (RelTransformerActor)
namespace {
constexpr int B_  = 128;
constexpr int T_  = 128;
constexpr int K_  = 8;
constexpr int H_  = 3;
constexpr int HK_ = 24;
constexpr int HID_ = 256;
constexpr int OUT_ = 2;
constexpr int PBS_ = 136;  // P row stride (bf16): 272B, 16B-aligned, banks spread
constexpr int X1S_ = 264;  // x1 row stride (bf16): 528B
constexpr int NPREP_ = 36; // producer blocks (32 W2 + 4 W1)
}

typedef __attribute__((ext_vector_type(8))) short bf16x8;
typedef __attribute__((ext_vector_type(4))) float f32x4;

__device__ inline unsigned short f2bf(float x) {           // RNE fp32->bf16
    unsigned int u = __float_as_uint(x);
    u += 0x7FFFu + ((u >> 16) & 1u);
    return (unsigned short)(u >> 16);
}
__device__ inline float bf2f(unsigned short v) { return __uint_as_float((unsigned)v << 16); }

// Cross-lane add via DPP (VALU pipe, not DS).
template <int CTRL>
__device__ inline float dpp_add(float v) {
    int t = __builtin_amdgcn_update_dpp(0, __float_as_int(v), CTRL, 0xF, 0xF, true);
    return v + __int_as_float(t);
}
__device__ inline float red16(float v) {   // sum over 16-lane groups
    v = dpp_add<0xB1>(v);     // quad_perm lane^1
    v = dpp_add<0x4E>(v);     // quad_perm lane^2
    v = dpp_add<0x141>(v);    // row_half_mirror
    return dpp_add<0x140>(v); // row_mirror
}

// ---------------------------------------------------------------------------
// Single-launch merged kernel.
//  blocks 0..35   (producers): W1 [32][256] -> w1t bf16 [n][k=32];
//                 W2 [256][256] -> w2t bf16 [n][k=256] (MFMA B-frag layout);
//                 then device-scope release of flags[blk] = 1.
//  blocks 36..291 (actors): block = (b, half of T): 64 rows, 4 waves; wave w
//                 owns rows [w*16,w*16+16) end-to-end S->PV->x1 (wave-private
//                 arena, no __syncthreads inside). Acquire-spin on flags just
//                 before x1 (prep overlaps the whole attention phase).
// Deadlock-safe: 292 blocks all co-resident (60 KB LDS -> 2 blocks/CU cap);
// producers never wait. Flags poison 0xAAAAAAAA != 1 -> spin is well-defined.
// Identities: softmax shift-invariance kills Kp[i]; sum w = 1 turns Vp[i]
// into a subtraction.
// ---------------------------------------------------------------------------
__global__ __launch_bounds__(256, 1) void fused_actor_kernel(
    const float* __restrict__ state,
    const float* __restrict__ noise,
    const float* __restrict__ Wq, const float* __restrict__ Wk,
    const float* __restrict__ Wv,
    const float* __restrict__ W1, const float* __restrict__ b1,
    const float* __restrict__ W2, const float* __restrict__ b2,
    const float* __restrict__ Wmu, const float* __restrict__ bmu,
    const float* __restrict__ Wls, const float* __restrict__ bls,
    unsigned short* __restrict__ w1t, unsigned short* __restrict__ w2t,
    unsigned int* __restrict__ flags,
    float* __restrict__ out)
{
    __shared__ float wq_s[K_*HK_], wk_s[K_*HK_], wv_s[K_*HK_]; // 2.25 KB
    __shared__ alignas(16) unsigned short Qb[64][HK_];       // 3 KB (row 48B)
    __shared__ alignas(16) unsigned short Kb[H_][T_][8];     // 6 KB (row 16B)
    __shared__ alignas(16) unsigned short Vt[H_][K_][T_];    // 6 KB (row 256B)
    __shared__ alignas(16) float lsw[4][H_][16];             // 768 B
    __shared__ alignas(16) unsigned short a0b[64][40];       // 5 KB (row 80B)
    __shared__ union alignas(16) Arena {                     // per-wave arena
        unsigned short P[16][PBS_];                          // 4.25 KB
        unsigned short x1[16][X1S_];                         // 8.25 KB
    } arena[4];                                              // 33 KB
    __shared__ alignas(16) float hp[4][64][4];               // 4 KB

    const int tid = threadIdx.x;
    const int blk = blockIdx.x;

    // ================= producer blocks =================
    if (blk < NPREP_) {
        unsigned short tmp[8];
        if (blk < 32) {
            const int k0 = blk * 8;
            #pragma unroll
            for (int i = 0; i < 8; ++i) tmp[i] = f2bf(W2[(size_t)(k0+i)*HID_ + tid]);
            *(bf16x8*)(w2t + (size_t)tid*256 + k0) = *(const bf16x8*)tmp;
        } else {
            const int k0 = (blk - 32) * 8;
            #pragma unroll
            for (int i = 0; i < 8; ++i) tmp[i] = f2bf(W1[(size_t)(k0+i)*HID_ + tid]);
            *(bf16x8*)(w1t + (size_t)tid*32 + k0) = *(const bf16x8*)tmp;
        }
        __syncthreads();               // all block stores issued
        if (tid == 0) {
            __threadfence();           // agent fence: writes visible device-wide
            __hip_atomic_store(&flags[blk], 1u, __ATOMIC_RELEASE,
                               __HIP_MEMORY_SCOPE_AGENT);
        }
        return;
    }

    // ================= actor blocks =================
    const int blk2 = blk - NPREP_;
    const int b    = blk2 >> 1;
    const int i0   = (blk2 & 1) * 64;            // 64-row slice of T
    const int w    = tid >> 6;
    const int lq   = (tid >> 4) & 3;   // MFMA quad: k-chunk (A/B) / row-group (C/D)
    const int ln   = tid & 15;         // MFMA m (A) / n (B, C/D cols)
    const float* sb = state + (size_t)b*T_*K_;

    // ---- stage qkv weights; prefetch input-resident biases/head weights ----
    if (tid < K_*HK_) { wq_s[tid]=Wq[tid]; wk_s[tid]=Wk[tid]; wv_s[tid]=Wv[tid]; }
    float b1v[16];
    #pragma unroll
    for (int nt = 0; nt < 16; ++nt) b1v[nt] = b1[nt*16 + ln];
    float b2v[4];
    float2 wmv[4], wlv[4];
    #pragma unroll
    for (int nt = 0; nt < 4; ++nt) {
        const int n0 = (w*4 + nt)*16 + ln;
        b2v[nt] = b2[n0];
        wmv[nt] = *(const float2*)(Wmu + n0*OUT_);
        wlv[nt] = *(const float2*)(Wls + n0*OUT_);
    }
    __syncthreads();                                   // barrier 1

    // ---- projections (cooperative): thread = (j, K-or-V) ----
    {
        const int j = tid >> 1, p = tid & 1;
        const float4 s0 = *(const float4*)(sb + j*8);
        const float4 s1 = *(const float4*)(sb + j*8 + 4);
        const float sv[8] = {s0.x,s0.y,s0.z,s0.w,s1.x,s1.y,s1.z,s1.w};
        const float* ws = p ? wv_s : wk_s;
        #pragma unroll
        for (int h = 0; h < H_; ++h) {
            unsigned short pk[8];
            #pragma unroll
            for (int k = 0; k < 8; ++k) {
                const int col = h*8 + k;
                float a = 0.f;
                #pragma unroll
                for (int m = 0; m < K_; ++m) a = fmaf(sv[m], ws[m*HK_+col], a);
                pk[k] = f2bf(a);
            }
            if (p == 0) {
                *(bf16x8*)&Kb[h][j][0] = *(const bf16x8*)pk;
            } else {
                #pragma unroll
                for (int d = 0; d < 8; ++d) Vt[h][d][j] = pk[d];  // transposed V
            }
        }
        // concat-state columns of a0b (block's 64 rows), bf16-packed
        if (p == 0 && j >= i0 && j < i0 + 64) {
            unsigned short sb16[8];
            #pragma unroll
            for (int k = 0; k < 8; ++k) sb16[k] = f2bf(sv[k]);
            *(bf16x8*)&a0b[j - i0][HK_] = *(const bf16x8*)sb16;
        }
    }
    // ---- Q projection (bf16, pre-scaled 1/sqrt(8)): 6 cols of one row ----
    {
        const int il = tid >> 2;               // 0..63
        const int c0 = (tid & 3) * 6;
        const float4 s0 = *(const float4*)(sb + (i0+il)*8);
        const float4 s1 = *(const float4*)(sb + (i0+il)*8 + 4);
        const float sv[8] = {s0.x,s0.y,s0.z,s0.w,s1.x,s1.y,s1.z,s1.w};
        #pragma unroll
        for (int cc = 0; cc < 6; ++cc) {
            const int col = c0 + cc;
            float aq = 0.f;
            #pragma unroll
            for (int m = 0; m < K_; ++m) aq = fmaf(sv[m], wq_s[m*HK_+col], aq);
            Qb[il][col] = f2bf(aq * 0.35355339059327373f);
        }
    }
    __syncthreads();                                   // barrier 2

    // ================= wave-private phase: rows rw..rw+16 =================
    const int rw = w*16;                   // block-local first row of wave
    Arena* ar = &arena[w];

    // ---- S = Q@K^T (24 MFMAs), exp+mask, P->arena, row-sums via DPP ----
    {
        const bf16x8 zf = {0,0,0,0,0,0,0,0};
        const f32x4 c0v = {0.f,0.f,0.f,0.f};
        float esum[H_][4];
        #pragma unroll
        for (int h = 0; h < H_; ++h)
            #pragma unroll
            for (int r = 0; r < 4; ++r) esum[h][r] = 0.f;
        #pragma unroll
        for (int h = 0; h < H_; ++h) {
            const bf16x8 tq = *(const bf16x8*)&Qb[rw + ln][h*8];
            const bf16x8 qa = (lq == 0) ? tq : zf;
            #pragma unroll
            for (int nt = 0; nt < 8; ++nt) {
                const bf16x8 tb = *(const bf16x8*)&Kb[h][nt*16 + ln][0];
                const bf16x8 kf = (lq == 0) ? tb : zf;
                f32x4 s = __builtin_amdgcn_mfma_f32_16x16x32_bf16(qa, kf, c0v, 0,0,0);
                #pragma unroll
                for (int r = 0; r < 4; ++r) {
                    const int rl = lq*4 + r;             // row within wave tile
                    const int j  = nt*16 + ln;
                    const float e = (j == i0 + rw + rl) ? 0.f : __expf(s[r]);
                    esum[h][r] += e;
                    ar->P[rl][j] = f2bf(e);
                }
            }
        }
        #pragma unroll
        for (int h = 0; h < H_; ++h)
            #pragma unroll
            for (int r = 0; r < 4; ++r) {
                const float v = red16(esum[h][r]);
                if (ln == 0) lsw[w][h][lq*4 + r] = v;
            }
    }
    // (no __syncthreads: same-wave LDS RAW, compiler orders via lgkmcnt)

    // ---- X = P@V (12 MFMAs); epilogue: /l - Vp[i] -> a0b ----
    {
        const bf16x8 zf = {0,0,0,0,0,0,0,0};
        #pragma unroll
        for (int h = 0; h < H_; ++h) {
            f32x4 x = {0.f,0.f,0.f,0.f};
            #pragma unroll
            for (int ks = 0; ks < 4; ++ks) {
                const bf16x8 pa = *(const bf16x8*)&ar->P[ln][ks*32 + lq*8];
                const bf16x8 tv = *(const bf16x8*)&Vt[h][ln & 7][ks*32 + lq*8];
                const bf16x8 vf = (ln < 8) ? tv : zf;
                x = __builtin_amdgcn_mfma_f32_16x16x32_bf16(pa, vf, x, 0, 0, 0);
            }
            if (ln < 8) {
                #pragma unroll
                for (int r = 0; r < 4; ++r) {
                    const int rl = lq*4 + r;
                    const float l = lsw[w][h][rl];
                    const float xatt = x[r] / l - bf2f(Vt[h][ln][i0 + rw + rl]);
                    a0b[rw + rl][h*8 + ln] = f2bf(xatt);
                }
            }
        }
    }

    // ---- acquire producer flags (prep overlapped the whole attention) ----
    if (tid < NPREP_) {
        while (__hip_atomic_load(&flags[tid], __ATOMIC_ACQUIRE,
                                 __HIP_MEMORY_SCOPE_AGENT) != 1u) {
            __builtin_amdgcn_s_sleep(1);
        }
    }
    __syncthreads();                                   // barrier 3 (flags + arena reuse)

    // ---- x1 = relu([x||state] @ W1 + b1): 16 MFMAs, full N=256 ----
    {
        bf16x8 w1f[16];
        #pragma unroll
        for (int nt = 0; nt < 16; ++nt)
            w1f[nt] = *(const bf16x8*)(w1t + (size_t)(nt*16+ln)*32 + lq*8);
        const bf16x8 a0 = *(const bf16x8*)&a0b[rw + ln][lq*8];
        #pragma unroll
        for (int nt = 0; nt < 16; ++nt) {
            const float bias = b1v[nt];
            f32x4 c = {bias, bias, bias, bias};
            f32x4 d = __builtin_amdgcn_mfma_f32_16x16x32_bf16(a0, w1f[nt], c, 0, 0, 0);
            #pragma unroll
            for (int r = 0; r < 4; ++r)
                ar->x1[lq*4 + r][nt*16 + ln] = f2bf(fmaxf(d[r], 0.f));
        }
    }
    __syncthreads();                                   // barrier 4

    // ---- x2 = relu(x1 @ W2 + b2): M=64 (4 m-tiles), wave's N=64 slice ----
    f32x4 acc2[4][4];                      // [mt][nt]
    #pragma unroll
    for (int nt = 0; nt < 4; ++nt) {
        const float bias = b2v[nt];
        f32x4 c = {bias, bias, bias, bias};
        #pragma unroll
        for (int mt = 0; mt < 4; ++mt) acc2[mt][nt] = c;
    }
    #pragma unroll
    for (int ks = 0; ks < 8; ++ks) {
        bf16x8 a[4];
        #pragma unroll
        for (int mt = 0; mt < 4; ++mt)
            a[mt] = *(const bf16x8*)&arena[mt].x1[ln][ks*32 + lq*8];
        #pragma unroll
        for (int nt = 0; nt < 4; ++nt) {
            const bf16x8 bf = *(const bf16x8*)(w2t + (size_t)((w*4+nt)*16+ln)*256 + ks*32 + lq*8);
            #pragma unroll
            for (int mt = 0; mt < 4; ++mt)
                acc2[mt][nt] = __builtin_amdgcn_mfma_f32_16x16x32_bf16(a[mt], bf, acc2[mt][nt], 0,0,0);
        }
    }

    // ---- heads: relu(x2).{Wmu,Wls}; DPP 16-lane reduce over n-lanes ----
    {
        float p[4][4][4];                  // [mt][r][o]
        #pragma unroll
        for (int mt = 0; mt < 4; ++mt)
            #pragma unroll
            for (int r = 0; r < 4; ++r)
                #pragma unroll
                for (int o = 0; o < 4; ++o) p[mt][r][o] = 0.f;
        #pragma unroll
        for (int nt = 0; nt < 4; ++nt) {
            const float2 wm = wmv[nt];
            const float2 wl = wlv[nt];
            #pragma unroll
            for (int mt = 0; mt < 4; ++mt) {
                #pragma unroll
                for (int r = 0; r < 4; ++r) {
                    const float x2 = fmaxf(acc2[mt][nt][r], 0.f);
                    p[mt][r][0] = fmaf(x2, wm.x, p[mt][r][0]);
                    p[mt][r][1] = fmaf(x2, wm.y, p[mt][r][1]);
                    p[mt][r][2] = fmaf(x2, wl.x, p[mt][r][2]);
                    p[mt][r][3] = fmaf(x2, wl.y, p[mt][r][3]);
                }
            }
        }
        #pragma unroll
        for (int mt = 0; mt < 4; ++mt)
            #pragma unroll
            for (int r = 0; r < 4; ++r)
                #pragma unroll
                for (int o = 0; o < 4; ++o)
                    p[mt][r][o] = red16(p[mt][r][o]);
        if (ln == 0) {
            #pragma unroll
            for (int mt = 0; mt < 4; ++mt)
                #pragma unroll
                for (int r = 0; r < 4; ++r) {
                    f32x4 pv = {p[mt][r][0], p[mt][r][1], p[mt][r][2], p[mt][r][3]};
                    *(f32x4*)&hp[w][mt*16 + lq*4 + r][0] = pv;
                }
        }
    }
    __syncthreads();                                   // barrier 5

    // ---- sampling tail: one thread per row ----
    if (tid < 64) {
        const int r = tid;
        const int grow = b*T_ + i0 + r;
        float pre[4];
        #pragma unroll
        for (int o = 0; o < 4; ++o)
            pre[o] = hp[0][r][o] + hp[1][r][o] + hp[2][r][o] + hp[3][r][o];
        float lp = 0.f;
        #pragma unroll
        for (int o = 0; o < OUT_; ++o) {
            float mu  = tanhf(pre[o]   + bmu[o]);
            float lsp = tanhf(pre[2+o] + bls[o]);
            float log_std = -20.f + 11.f * (lsp + 1.f);
            float sd = __expf(log_std);
            float n  = noise[(size_t)grow*OUT_ + o];
            float z  = fmaf(sd, n, mu);
            float a  = tanhf(z);
            out[(size_t)grow*OUT_ + o] = a;
            lp += -0.5f*n*n - log_std - 0.91893853320467274f
                  - logf(1.f - a*a + 1e-7f);
        }
        out[(size_t)B_*T_*OUT_ + grow] = lp;
    }
}

extern "C" void kernel_launch(void* const* d_in, const int* in_sizes, int n_in,
                              void* d_out, int out_size, void* d_ws, size_t ws_size,
                              hipStream_t stream)
{
    const float* state = (const float*)d_in[0];
    const float* noise = (const float*)d_in[1];
    const float* Wq  = (const float*)d_in[2];
    const float* Wk  = (const float*)d_in[3];
    const float* Wv  = (const float*)d_in[4];
    const float* W1  = (const float*)d_in[5];
    const float* b1  = (const float*)d_in[6];
    const float* W2  = (const float*)d_in[7];
    const float* b2  = (const float*)d_in[8];
    const float* Wmu = (const float*)d_in[9];
    const float* bmu = (const float*)d_in[10];
    const float* Wls = (const float*)d_in[11];
    const float* bls = (const float*)d_in[12];
    float* out = (float*)d_out;

    unsigned short* w1t = (unsigned short*)d_ws;            // 8192 bf16 = 16 KB
    unsigned short* w2t = w1t + 8192;                       // 65536 bf16 = 128 KB
    unsigned int*  flags = (unsigned int*)(w2t + 65536);    // 36 cells (poison != 1)

    fused_actor_kernel<<<dim3(NPREP_ + B_*2), dim3(256), 0, stream>>>(
        state, noise, Wq, Wk, Wv, W1, b1, W2, b2, Wmu, bmu, Wls, bls,
        w1t, w2t, flags, out);
}